// Round 2
// baseline (617.471 us; speedup 1.0000x reference)
//
#include <hip/hip_runtime.h>

typedef _Float16 half8 __attribute__((ext_vector_type(8)));
typedef _Float16 half4 __attribute__((ext_vector_type(4)));
typedef float    floatx4 __attribute__((ext_vector_type(4)));

#define NB  16
#define SEQ 2048
#define DIM 64
#define EST 2056  // ebuf row stride in halves (2048 + 8 pad: breaks pow-2 bank aliasing)

// ---- pre-pass: q,k fp32 -> f16 (straight copy-convert) ----
__global__ __launch_bounds__(256) void cvt_qk_kernel(const float* __restrict__ q,
                                                     const float* __restrict__ k,
                                                     _Float16* __restrict__ qh,
                                                     _Float16* __restrict__ kh) {
    size_t i = ((size_t)blockIdx.x * 256 + threadIdx.x) * 4;
    float4 a = *(const float4*)(q + i);
    float4 b = *(const float4*)(k + i);
    half4 ha = { (_Float16)a.x, (_Float16)a.y, (_Float16)a.z, (_Float16)a.w };
    half4 hb = { (_Float16)b.x, (_Float16)b.y, (_Float16)b.z, (_Float16)b.w };
    *(half4*)(qh + i) = ha;
    *(half4*)(kh + i) = hb;
}

// ---- pre-pass: v [B][S][D] fp32 -> vt [B][D][S] f16 (LDS tile transpose) ----
__global__ __launch_bounds__(256) void cvt_vt_kernel(const float* __restrict__ v,
                                                     _Float16* __restrict__ vt) {
    __shared__ float tile[64][65];
    const int b  = blockIdx.x >> 5;
    const int s0 = (blockIdx.x & 31) << 6;
    const int t  = threadIdx.x;
    {
        const int row = t >> 2;            // s-local 0..63
        const int c0  = (t & 3) << 4;      // d base
        const float* src = v + ((size_t)(b * SEQ + s0 + row)) * DIM + c0;
        #pragma unroll
        for (int i = 0; i < 4; ++i) {
            float4 x = *(const float4*)(src + i * 4);
            tile[row][c0 + i*4 + 0] = x.x;
            tile[row][c0 + i*4 + 1] = x.y;
            tile[row][c0 + i*4 + 2] = x.z;
            tile[row][c0 + i*4 + 3] = x.w;
        }
    }
    __syncthreads();
    {
        const int d  = t >> 2;             // 0..63
        const int sb = (t & 3) << 4;       // s-local base
        _Float16* dst = vt + ((size_t)(b * DIM + d)) * SEQ + s0 + sb;
        #pragma unroll
        for (int i = 0; i < 4; ++i) {
            half4 h = { (_Float16)tile[sb + i*4 + 0][d],
                        (_Float16)tile[sb + i*4 + 1][d],
                        (_Float16)tile[sb + i*4 + 2][d],
                        (_Float16)tile[sb + i*4 + 3][d] };
            *(half4*)(dst + i*4) = h;
        }
    }
}

// ---- fused attention: one block = 16 q-rows of one b ----
// Wave w computes score col-tiles jt ≡ w (mod 4); e stashed f16 in LDS;
// PV computed as out^T = V^T @ e^T (e-as-B frag == e-as-A frag layout).
__global__ __launch_bounds__(256) void attn_kernel(
    const _Float16* __restrict__ qh, const _Float16* __restrict__ kh,
    const _Float16* __restrict__ vt, const int* __restrict__ mask,
    float* __restrict__ out, float* __restrict__ attn)
{
    __shared__ _Float16 ebuf[16][EST];
    __shared__ float lsum[16];

    const int b    = blockIdx.x >> 7;
    const int r0   = (blockIdx.x & 127) << 4;
    const int lane = threadIdx.x & 63;
    const int wave = threadIdx.x >> 6;
    const int rl   = lane & 15;   // MFMA m/n index
    const int g    = lane >> 4;   // quad

    if (threadIdx.x < 16) lsum[threadIdx.x] = 0.0f;
    __syncthreads();

    // Q A-fragments (rows r0..r0+15), d split into two K=32 chunks
    const size_t qoff = ((size_t)(b * SEQ + r0 + rl)) * DIM + g * 8;
    half8 qa0 = *(const half8*)(qh + qoff);
    half8 qa1 = *(const half8*)(qh + qoff + 32);

    const _Float16* kbase = kh + (size_t)b * SEQ * DIM + (size_t)rl * DIM + g * 8;
    // mask is int32 (harness delivers bool as int): element-indexed
    const int* mbase = mask + ((size_t)(b * SEQ + r0 + g * 4)) * SEQ + rl;

    float rs0 = 0.f, rs1 = 0.f, rs2 = 0.f, rs3 = 0.f;

    for (int jt = wave; jt < 128; jt += 4) {
        const int j0 = jt << 4;
        const _Float16* kp = kbase + (size_t)j0 * DIM;
        half8 kb0 = *(const half8*)kp;          // K[j0+rl][g*8 .. +7]
        half8 kb1 = *(const half8*)(kp + 32);   // K[j0+rl][32+g*8 .. +7]
        floatx4 c = {0.f, 0.f, 0.f, 0.f};
        c = __builtin_amdgcn_mfma_f32_16x16x32_f16(qa0, kb0, c, 0, 0, 0);
        c = __builtin_amdgcn_mfma_f32_16x16x32_f16(qa1, kb1, c, 0, 0, 0);
        // c[i] = raw score[row = g*4+i][col = j0+rl]
        const int* mp = mbase + j0;
        float e0 = mp[0]         ? 0.f : __expf(c[0] * 0.125f);
        float e1 = mp[SEQ]       ? 0.f : __expf(c[1] * 0.125f);
        float e2 = mp[2*SEQ]     ? 0.f : __expf(c[2] * 0.125f);
        float e3 = mp[3*SEQ]     ? 0.f : __expf(c[3] * 0.125f);
        rs0 += e0; rs1 += e1; rs2 += e2; rs3 += e3;
        ebuf[g*4 + 0][j0 + rl] = (_Float16)e0;
        ebuf[g*4 + 1][j0 + rl] = (_Float16)e1;
        ebuf[g*4 + 2][j0 + rl] = (_Float16)e2;
        ebuf[g*4 + 3][j0 + rl] = (_Float16)e3;
    }

    // row-sum reduction: cols of a row live in the 16 lanes of a quad
    float rsv[4] = {rs0, rs1, rs2, rs3};
    #pragma unroll
    for (int i = 0; i < 4; ++i) {
        float v = rsv[i];
        v += __shfl_xor(v, 1);
        v += __shfl_xor(v, 2);
        v += __shfl_xor(v, 4);
        v += __shfl_xor(v, 8);
        if (rl == 0) atomicAdd(&lsum[g*4 + i], v);
    }
    __syncthreads();

    // ---- PV: wave owns d-slice [16*wave, 16*wave+16) ----
    floatx4 oacc = {0.f, 0.f, 0.f, 0.f};
    const _Float16* vbase = vt + ((size_t)(b * DIM + wave * 16 + rl)) * SEQ + g * 8;
    #pragma unroll 4
    for (int jc = 0; jc < 64; ++jc) {
        half8 va = *(const half8*)(vbase + jc * 32);                 // A = V^T[d][j..]
        half8 eb = *(const half8*)(&ebuf[rl][jc * 32 + g * 8]);      // B = e^T (A-layout of e)
        oacc = __builtin_amdgcn_mfma_f32_16x16x32_f16(va, eb, oacc, 0, 0, 0);
    }
    {
        // oacc[i] = out[r0+rl][16*wave + g*4 + i] (unnormalized)
        const float inv = 1.0f / lsum[rl];
        floatx4 ov = { oacc[0]*inv, oacc[1]*inv, oacc[2]*inv, oacc[3]*inv };
        float* op = out + ((size_t)(b * SEQ + r0 + rl)) * DIM + wave * 16 + g * 4;
        *(floatx4*)op = ov;
    }

    // ---- attn epilogue: normalized fp32, fully coalesced float4 stores ----
    {
        const int row  = threadIdx.x >> 4;  // 0..15
        const int cseg = threadIdx.x & 15;
        const float inv = 1.0f / lsum[row];
        float* ap = attn + ((size_t)(b * SEQ + r0 + row)) * SEQ;
        #pragma unroll
        for (int it = 0; it < 16; ++it) {
            const int c0 = cseg * 8 + it * 128;
            half8 ev = *(const half8*)(&ebuf[row][c0]);
            floatx4 lo = { (float)ev[0]*inv, (float)ev[1]*inv, (float)ev[2]*inv, (float)ev[3]*inv };
            floatx4 hi = { (float)ev[4]*inv, (float)ev[5]*inv, (float)ev[6]*inv, (float)ev[7]*inv };
            *(floatx4*)(ap + c0)     = lo;
            *(floatx4*)(ap + c0 + 4) = hi;
        }
    }
}

extern "C" void kernel_launch(void* const* d_in, const int* in_sizes, int n_in,
                              void* d_out, int out_size, void* d_ws, size_t ws_size,
                              hipStream_t stream) {
    const float* q = (const float*)d_in[0];
    const float* k = (const float*)d_in[1];
    const float* v = (const float*)d_in[2];
    const int* mask = (const int*)d_in[3];   // bool delivered as int32 per harness

    float* out  = (float*)d_out;                       // [16,2048,64]
    float* attn = out + (size_t)NB * SEQ * DIM;        // [16,2048,2048]

    // workspace: qh | kh | vt  (f16, 4 MB each = 12 MB total)
    _Float16* qh = (_Float16*)d_ws;
    _Float16* kh = qh + (size_t)NB * SEQ * DIM;
    _Float16* vt = kh + (size_t)NB * SEQ * DIM;

    cvt_qk_kernel<<<(NB * SEQ * DIM) / 1024, 256, 0, stream>>>(q, k, qh, kh);
    cvt_vt_kernel<<<NB * (SEQ / 64), 256, 0, stream>>>(v, vt);
    attn_kernel<<<NB * (SEQ / 16), 256, 0, stream>>>(qh, kh, vt, mask, out, attn);
}